// Round 1
// baseline (223.400 us; speedup 1.0000x reference)
//
#include <hip/hip_runtime.h>

// Problem constants (from reference): AA [NF,NLOC,NNEI,NNEI,NH] f32,
// h2 [NF,NLOC,NNEI,3] f32, w [NH,1] f32 -> out [NF,NLOC,NNEI,3] f32.
#define NF   4
#define NLOC 1024
#define NNEI 128
#define NH   4

// out[b,n,i,d] = sum_j ( sum_h AA[b,n,i,j,h]*w[h] ) * h2[b,n,j,d]
//
// One block per (b,n). 256 threads = 4 waves; wave handles 32 i-rows.
// Lanes cover j: lane handles j=lane and j=lane+64 -> coalesced float4
// loads (h is innermost, NH=4 floats = 16B). h2 for the lane's two j's
// is loop-invariant -> kept in 6 registers; no LDS.
__global__ __launch_bounds__(256) void
a2ev_kernel(const float4* __restrict__ AA4,
            const float* __restrict__ h2,
            const float* __restrict__ w,
            float* __restrict__ out) {
    const int bn   = blockIdx.x;        // 0..NF*NLOC-1
    const int tid  = threadIdx.x;
    const int lane = tid & 63;
    const int wave = tid >> 6;          // 0..3

    const float w0 = w[0], w1 = w[1], w2 = w[2], w3 = w[3];

    const float* h2b = h2 + (size_t)bn * (NNEI * 3);
    const float hx0 = h2b[lane * 3 + 0];
    const float hy0 = h2b[lane * 3 + 1];
    const float hz0 = h2b[lane * 3 + 2];
    const float hx1 = h2b[(lane + 64) * 3 + 0];
    const float hy1 = h2b[(lane + 64) * 3 + 1];
    const float hz1 = h2b[(lane + 64) * 3 + 2];

    const size_t base = (size_t)bn * (NNEI * NNEI);  // in float4 units
    float* outb = out + (size_t)bn * (NNEI * 3);

    #pragma unroll 4
    for (int ii = 0; ii < 32; ++ii) {
        const int i = wave * 32 + ii;
        const float4 a0 = AA4[base + (size_t)i * NNEI + lane];
        const float4 a1 = AA4[base + (size_t)i * NNEI + lane + 64];

        const float s0 = a0.x * w0 + a0.y * w1 + a0.z * w2 + a0.w * w3;
        const float s1 = a1.x * w0 + a1.y * w1 + a1.z * w2 + a1.w * w3;

        float px = s0 * hx0 + s1 * hx1;
        float py = s0 * hy0 + s1 * hy1;
        float pz = s0 * hz0 + s1 * hz1;

        // Butterfly reduce over the 64-lane wave.
        #pragma unroll
        for (int off = 32; off > 0; off >>= 1) {
            px += __shfl_xor(px, off, 64);
            py += __shfl_xor(py, off, 64);
            pz += __shfl_xor(pz, off, 64);
        }

        if (lane == 0) {
            outb[i * 3 + 0] = px;
            outb[i * 3 + 1] = py;
            outb[i * 3 + 2] = pz;
        }
    }
}

extern "C" void kernel_launch(void* const* d_in, const int* in_sizes, int n_in,
                              void* d_out, int out_size, void* d_ws, size_t ws_size,
                              hipStream_t stream) {
    const float4* AA4 = (const float4*)d_in[0];
    const float*  h2  = (const float*)d_in[1];
    const float*  w   = (const float*)d_in[2];
    float* out = (float*)d_out;

    dim3 grid(NF * NLOC);
    dim3 block(256);
    a2ev_kernel<<<grid, block, 0, stream>>>(AA4, h2, w, out);
}

// Round 3
// 175.919 us; speedup vs baseline: 1.2699x; 1.2699x over previous
//
#include <hip/hip_runtime.h>

#define NF   4
#define NLOC 1024
#define NNEI 128
#define NH   4

typedef float f32x4 __attribute__((ext_vector_type(4)));

// out[b,n,i,d] = sum_j ( sum_h AA[b,n,i,j,h]*w[h] ) * h2[b,n,j,d]
//
// One block per (b,n); 256 threads = 4 waves; wave handles 32 i-rows.
// Lane decomposition: lane = i_sub*16 + j_sub. Each 16-lane group owns one
// i-row; lane accumulates j = j_sub + 16t (t=0..7) fully in registers
// (h2 for those 8 j's is loop-invariant -> 24 VGPRs). Reduce is 4
// ds_swizzle xor-stages over 16 lanes, retiring 4 rows per sequence
// (3 shuffles/row vs 18 in the previous version).

// single-instruction butterfly step within 32-lane group (BitMode xor)
#define SWZ_ADD(v, m) \
    v += __int_as_float(__builtin_amdgcn_ds_swizzle(__float_as_int(v), ((m) << 10) | 0x1F))

__global__ __launch_bounds__(256) void
a2ev_kernel(const f32x4* __restrict__ AA4,
            const float* __restrict__ h2,
            const float* __restrict__ w,
            float* __restrict__ out) {
    const int bn   = blockIdx.x;        // 0..NF*NLOC-1
    const int tid  = threadIdx.x;
    const int lane = tid & 63;
    const int wave = tid >> 6;          // 0..3
    const int isub = lane >> 4;         // 0..3  (which row of the group of 4)
    const int jsub = lane & 15;         // 0..15 (j phase)

    const float w0 = w[0], w1 = w[1], w2 = w[2], w3 = w[3];

    // h2 components for this lane's 8 j-values, held in registers.
    const float* h2b = h2 + (size_t)bn * (NNEI * 3);
    float hx[8], hy[8], hz[8];
    #pragma unroll
    for (int t = 0; t < 8; ++t) {
        const int j = jsub + 16 * t;
        hx[t] = h2b[j * 3 + 0];
        hy[t] = h2b[j * 3 + 1];
        hz[t] = h2b[j * 3 + 2];
    }

    const size_t base = (size_t)bn * (NNEI * NNEI);  // float4 units
    float* outb = out + (size_t)bn * (NNEI * 3);

    #pragma unroll 2
    for (int g = 0; g < 8; ++g) {
        const int i = wave * 32 + g * 4 + isub;
        const f32x4* rowp = AA4 + base + (size_t)i * NNEI + jsub;

        float px = 0.f, py = 0.f, pz = 0.f;
        #pragma unroll
        for (int t = 0; t < 8; ++t) {
            const f32x4 a = __builtin_nontemporal_load(&rowp[16 * t]);
            const float s = a.x * w0 + a.y * w1 + a.z * w2 + a.w * w3;
            px += s * hx[t];
            py += s * hy[t];
            pz += s * hz[t];
        }

        // 16-lane butterfly reduce; 4 i-rows retire simultaneously.
        SWZ_ADD(px, 1);  SWZ_ADD(py, 1);  SWZ_ADD(pz, 1);
        SWZ_ADD(px, 2);  SWZ_ADD(py, 2);  SWZ_ADD(pz, 2);
        SWZ_ADD(px, 4);  SWZ_ADD(py, 4);  SWZ_ADD(pz, 4);
        SWZ_ADD(px, 8);  SWZ_ADD(py, 8);  SWZ_ADD(pz, 8);

        if (jsub == 0) {
            outb[i * 3 + 0] = px;
            outb[i * 3 + 1] = py;
            outb[i * 3 + 2] = pz;
        }
    }
}

extern "C" void kernel_launch(void* const* d_in, const int* in_sizes, int n_in,
                              void* d_out, int out_size, void* d_ws, size_t ws_size,
                              hipStream_t stream) {
    const f32x4* AA4 = (const f32x4*)d_in[0];
    const float* h2  = (const float*)d_in[1];
    const float* w   = (const float*)d_in[2];
    float* out = (float*)d_out;

    dim3 grid(NF * NLOC);
    dim3 block(256);
    a2ev_kernel<<<grid, block, 0, stream>>>(AA4, h2, w, out);
}